// Round 1
// baseline (560.830 us; speedup 1.0000x reference)
//
#include <hip/hip_runtime.h>

#define SL     32768   // S*L
#define S_DIM  128
#define L_DIM  256
#define D_DIM  128
#define H_DIM  4
#define C_DIM  32
#define EPS_LN 1e-5f

// ---------------------------------------------------------------------------
// K1/K4: QKV projection  qkv[o,s,l] = sum_d w[o,d]*in[d,s,l] + b[o]
// grid 512: bid -> (s = bid>>2, quarter = bid&3 -> l0 = quarter*64)
// block 256. LDS: x tile [128 d][64 l] = 32KB.
// Each thread: 2 consecutive l (float2), 48 o in chunks of 4 -> 12.3K FMA.
// ---------------------------------------------------------------------------
__global__ __launch_bounds__(256) void qkv_kernel(const float* __restrict__ in,
                                                  const float* __restrict__ w,
                                                  const float* __restrict__ b,
                                                  float* __restrict__ qkv) {
    __shared__ float xt[128][64];
    const int bid = blockIdx.x;
    const int s  = bid >> 2;
    const int l0 = (bid & 3) * 64;
    const int tid = threadIdx.x;

    for (int idx = tid; idx < 128 * 64; idx += 256) {
        const int d = idx >> 6, l = idx & 63;
        xt[d][l] = in[d * SL + s * L_DIM + l0 + l];
    }
    __syncthreads();

    const int lp  = tid & 31;        // which float2 within the 64-l tile
    const int grp = tid >> 5;        // 8 groups x 48 outputs
    const int o0  = grp * 48;
    const float2* xt2 = (const float2*)&xt[0][0];   // xt2[d*32 + lp]

    for (int ob = 0; ob < 48; ob += 4) {
        const int o = o0 + ob;
        float2 acc[4];
        #pragma unroll
        for (int io = 0; io < 4; ++io) { acc[io].x = b[o + io]; acc[io].y = b[o + io]; }
        #pragma unroll 4
        for (int d = 0; d < 128; ++d) {
            const float2 xv = xt2[d * 32 + lp];
            #pragma unroll
            for (int io = 0; io < 4; ++io) {
                const float wv = w[(o + io) * 128 + d];
                acc[io].x += wv * xv.x;
                acc[io].y += wv * xv.y;
            }
        }
        #pragma unroll
        for (int io = 0; io < 4; ++io) {
            *(float2*)&qkv[(o + io) * SL + s * L_DIM + l0 + lp * 2] = acc[io];
        }
    }
}

// ---------------------------------------------------------------------------
// K2: row attention. grid 512: (h = bid>>7, s = bid&127), block 256 (thread = query i in L).
// LDS: K,V tiles [32][256] (64KB). Online softmax in registers.
// ---------------------------------------------------------------------------
__global__ __launch_bounds__(256) void row_attn_kernel(const float* __restrict__ qkv,
                                                       float* __restrict__ ao) {
    __shared__ float kt[32][256];
    __shared__ float vt[32][256];
    const int h = blockIdx.x >> 7;
    const int s = blockIdx.x & 127;
    const int tid = threadIdx.x;

    const float* kbase = qkv + (128 + h * 32) * SL + s * L_DIM;
    const float* vbase = qkv + (256 + h * 32) * SL + s * L_DIM;
    for (int idx = tid; idx < 32 * 256; idx += 256) {
        const int c = idx >> 8, j = idx & 255;
        kt[c][j] = kbase[c * SL + j];
        vt[c][j] = vbase[c * SL + j];
    }
    float qr[32];
    const float* qbase = qkv + (h * 32) * SL + s * L_DIM + tid;
    #pragma unroll
    for (int c = 0; c < 32; ++c) qr[c] = qbase[c * SL];
    __syncthreads();

    float m = -__builtin_inff(), lsum = 0.f;
    float o[32];
    #pragma unroll
    for (int d = 0; d < 32; ++d) o[d] = 0.f;

    for (int j = 0; j < 256; ++j) {
        float sc = 0.f;
        #pragma unroll
        for (int c = 0; c < 32; ++c) sc += qr[c] * kt[c][j];
        if (sc > m) {                       // rescale only on new max
            const float alpha = __expf(m - sc);
            lsum *= alpha;
            #pragma unroll
            for (int d = 0; d < 32; ++d) o[d] *= alpha;
            m = sc;
        }
        const float p = __expf(sc - m);
        lsum += p;
        #pragma unroll
        for (int d = 0; d < 32; ++d) o[d] += p * vt[d][j];
    }
    const float inv = 1.f / lsum;
    float* obase = ao + (h * 32) * SL + s * L_DIM + tid;
    #pragma unroll
    for (int d = 0; d < 32; ++d) obase[d * SL] = o[d] * inv;
}

// ---------------------------------------------------------------------------
// K5: column attention. grid 512: (h = bid>>7, lpair = bid&127 -> l0 = lpair*2).
// block 256: thread = (i = tid&127 query in S, lp = tid>>7 which l of the pair).
// LDS: K,V tiles [32][128 j][2 lp] = 64KB.
// ---------------------------------------------------------------------------
__global__ __launch_bounds__(256) void col_attn_kernel(const float* __restrict__ qkv,
                                                       float* __restrict__ ao) {
    __shared__ float kt[32][256];   // [c][j*2+lp]
    __shared__ float vt[32][256];
    const int h  = blockIdx.x >> 7;
    const int l0 = (blockIdx.x & 127) * 2;
    const int tid = threadIdx.x;
    const int i  = tid & 127;
    const int lp = tid >> 7;

    const float* kbase = qkv + (128 + h * 32) * SL + l0;
    const float* vbase = qkv + (256 + h * 32) * SL + l0;
    for (int idx = tid; idx < 32 * 256; idx += 256) {
        const int c = idx >> 8, rem = idx & 255;
        const int j = rem >> 1, p2 = rem & 1;
        kt[c][rem] = kbase[c * SL + j * L_DIM + p2];
        vt[c][rem] = vbase[c * SL + j * L_DIM + p2];
    }
    float qr[32];
    const float* qbase = qkv + (h * 32) * SL + i * L_DIM + l0 + lp;
    #pragma unroll
    for (int c = 0; c < 32; ++c) qr[c] = qbase[c * SL];
    __syncthreads();

    float m = -__builtin_inff(), lsum = 0.f;
    float o[32];
    #pragma unroll
    for (int d = 0; d < 32; ++d) o[d] = 0.f;

    for (int j = 0; j < 128; ++j) {
        float sc = 0.f;
        #pragma unroll
        for (int c = 0; c < 32; ++c) sc += qr[c] * kt[c][(j << 1) | lp];
        if (sc > m) {
            const float alpha = __expf(m - sc);
            lsum *= alpha;
            #pragma unroll
            for (int d = 0; d < 32; ++d) o[d] *= alpha;
            m = sc;
        }
        const float p = __expf(sc - m);
        lsum += p;
        #pragma unroll
        for (int d = 0; d < 32; ++d) o[d] += p * vt[d][(j << 1) | lp];
    }
    const float inv = 1.f / lsum;
    float* obase = ao + (h * 32) * SL + i * L_DIM + l0 + lp;
    #pragma unroll
    for (int d = 0; d < 32; ++d) obase[d * SL] = o[d] * inv;
}

// ---------------------------------------------------------------------------
// K3/K6: channel LayerNorm with residual: out = LN(a + r) * gamma + beta
// grid 128, block 256: one thread per (s,l) position, reduce over 128 channels.
// ---------------------------------------------------------------------------
__global__ __launch_bounds__(256) void ln_kernel(const float* __restrict__ a,
                                                 const float* __restrict__ r,
                                                 const float* __restrict__ gamma,
                                                 const float* __restrict__ beta,
                                                 float* __restrict__ out) {
    const int pos = blockIdx.x * 256 + threadIdx.x;
    float sum = 0.f, sumsq = 0.f;
    #pragma unroll 8
    for (int d = 0; d < 128; ++d) {
        const float v = a[d * SL + pos] + r[d * SL + pos];
        sum += v;
        sumsq += v * v;
    }
    const float mean = sum * (1.f / 128.f);
    const float var  = sumsq * (1.f / 128.f) - mean * mean;
    const float rstd = rsqrtf(var + EPS_LN);
    #pragma unroll 8
    for (int d = 0; d < 128; ++d) {
        const float v = a[d * SL + pos] + r[d * SL + pos];
        out[d * SL + pos] = (v - mean) * rstd * gamma[d] + beta[d];
    }
}

// ---------------------------------------------------------------------------
extern "C" void kernel_launch(void* const* d_in, const int* in_sizes, int n_in,
                              void* d_out, int out_size, void* d_ws, size_t ws_size,
                              hipStream_t stream) {
    const float* x     = (const float*)d_in[0];
    const float* w_row = (const float*)d_in[1];
    const float* b_row = (const float*)d_in[2];
    const float* w_col = (const float*)d_in[3];
    const float* b_col = (const float*)d_in[4];
    const float* g1    = (const float*)d_in[5];
    const float* be1   = (const float*)d_in[6];
    const float* g2    = (const float*)d_in[7];
    const float* be2   = (const float*)d_in[8];
    float* out = (float*)d_out;

    // workspace: qkv (384*SL) | attn_out (128*SL) | out1 (128*SL) = 80 MB
    float* qkv  = (float*)d_ws;
    float* ao   = qkv + 384 * SL;
    float* out1 = ao + 128 * SL;

    qkv_kernel<<<512, 256, 0, stream>>>(x, w_row, b_row, qkv);
    row_attn_kernel<<<512, 256, 0, stream>>>(qkv, ao);
    ln_kernel<<<128, 256, 0, stream>>>(x, ao, g1, be1, out1);
    qkv_kernel<<<512, 256, 0, stream>>>(out1, w_col, b_col, qkv);
    col_attn_kernel<<<512, 256, 0, stream>>>(qkv, ao);
    ln_kernel<<<128, 256, 0, stream>>>(out1, ao, g2, be2, out);
}

// Round 2
// 500.636 us; speedup vs baseline: 1.1202x; 1.1202x over previous
//
#include <hip/hip_runtime.h>

#define SL     32768   // S*L
#define S_DIM  128
#define L_DIM  256
#define D_DIM  128
#define H_DIM  4
#define C_DIM  32
#define EPS_LN 1e-5f

// ---------------------------------------------------------------------------
// K1/K4: QKV projection  qkv[o,s,l] = sum_d w[o,d]*in[d,s,l] + b[o]
// grid 512: bid -> (s = bid>>2, quarter = bid&3 -> l0 = quarter*64)
// block 256. LDS: x tile [128 d][64 l] = 32KB.
// ---------------------------------------------------------------------------
__global__ __launch_bounds__(256) void qkv_kernel(const float* __restrict__ in,
                                                  const float* __restrict__ w,
                                                  const float* __restrict__ b,
                                                  float* __restrict__ qkv) {
    __shared__ float xt[128][64];
    const int bid = blockIdx.x;
    const int s  = bid >> 2;
    const int l0 = (bid & 3) * 64;
    const int tid = threadIdx.x;

    for (int idx = tid; idx < 128 * 64; idx += 256) {
        const int d = idx >> 6, l = idx & 63;
        xt[d][l] = in[d * SL + s * L_DIM + l0 + l];
    }
    __syncthreads();

    const int lp  = tid & 31;        // which float2 within the 64-l tile
    const int grp = tid >> 5;        // 8 groups x 48 outputs
    const int o0  = grp * 48;
    const float2* xt2 = (const float2*)&xt[0][0];   // xt2[d*32 + lp]

    for (int ob = 0; ob < 48; ob += 4) {
        const int o = o0 + ob;
        float2 acc[4];
        #pragma unroll
        for (int io = 0; io < 4; ++io) { acc[io].x = b[o + io]; acc[io].y = b[o + io]; }
        #pragma unroll 4
        for (int d = 0; d < 128; ++d) {
            const float2 xv = xt2[d * 32 + lp];
            #pragma unroll
            for (int io = 0; io < 4; ++io) {
                const float wv = w[(o + io) * 128 + d];
                acc[io].x += wv * xv.x;
                acc[io].y += wv * xv.y;
            }
        }
        #pragma unroll
        for (int io = 0; io < 4; ++io) {
            *(float2*)&qkv[(o + io) * SL + s * L_DIM + l0 + lp * 2] = acc[io];
        }
    }
}

// ---------------------------------------------------------------------------
// K2: row attention. grid 512: (h = bid>>7, s = bid&127), block 256 (thread = query i in L).
// K/V staged in j-tiles of 64 -> LDS 16KB (was 64KB) for occupancy.
// ---------------------------------------------------------------------------
#define RJT 64
__global__ __launch_bounds__(256) void row_attn_kernel(const float* __restrict__ qkv,
                                                       float* __restrict__ ao) {
    __shared__ float kt[32][RJT];
    __shared__ float vt[32][RJT];
    const int h = blockIdx.x >> 7;
    const int s = blockIdx.x & 127;
    const int tid = threadIdx.x;

    const float* kbase = qkv + (128 + h * 32) * SL + s * L_DIM;
    const float* vbase = qkv + (256 + h * 32) * SL + s * L_DIM;

    float qr[32];
    const float* qbase = qkv + (h * 32) * SL + s * L_DIM + tid;
    #pragma unroll
    for (int c = 0; c < 32; ++c) qr[c] = qbase[c * SL];

    float m = -__builtin_inff(), lsum = 0.f;
    float o[32];
    #pragma unroll
    for (int d = 0; d < 32; ++d) o[d] = 0.f;

    for (int j0 = 0; j0 < 256; j0 += RJT) {
        __syncthreads();
        // load K,V j-tile: 32c x 64j floats each = 512 float4 per tensor
        for (int idx = tid; idx < 32 * (RJT / 4); idx += 256) {
            const int c  = idx >> 4;           // 16 float4 per c-row
            const int f4 = idx & 15;
            *(float4*)&kt[c][f4 * 4] = *(const float4*)&kbase[c * SL + j0 + f4 * 4];
            *(float4*)&vt[c][f4 * 4] = *(const float4*)&vbase[c * SL + j0 + f4 * 4];
        }
        __syncthreads();
        #pragma unroll 4
        for (int jj = 0; jj < RJT; ++jj) {
            float sc = 0.f;
            #pragma unroll
            for (int c = 0; c < 32; ++c) sc += qr[c] * kt[c][jj];
            if (sc > m) {
                const float alpha = __expf(m - sc);
                lsum *= alpha;
                #pragma unroll
                for (int d = 0; d < 32; ++d) o[d] *= alpha;
                m = sc;
            }
            const float p = __expf(sc - m);
            lsum += p;
            #pragma unroll
            for (int d = 0; d < 32; ++d) o[d] += p * vt[d][jj];
        }
    }
    const float inv = 1.f / lsum;
    float* obase = ao + (h * 32) * SL + s * L_DIM + tid;
    #pragma unroll
    for (int d = 0; d < 32; ++d) obase[d * SL] = o[d] * inv;
}

// ---------------------------------------------------------------------------
// K5: column attention (attend along S). Rebuilt for coalescing:
// grid 512: h(4) x i-tile(16, 8 queries) x l-tile(8, 32 l). block 256:
// thread = (ii = tid>>5 in [0,8), myl = tid&31). All global accesses walk l.
// K/V staged per j-tile (8 j) in LDS [32c][8j][32l] = 32KB each.
// ---------------------------------------------------------------------------
#define CJT 8
__global__ __launch_bounds__(256) void col_attn_kernel(const float* __restrict__ qkv,
                                                       float* __restrict__ ao) {
    __shared__ float kt[32][CJT][32];
    __shared__ float vt[32][CJT][32];
    const int bid = blockIdx.x;
    const int h  = bid >> 7;
    const int i0 = ((bid >> 3) & 15) * 8;
    const int l0 = (bid & 7) * 32;
    const int tid = threadIdx.x;
    const int myl = tid & 31;
    const int ii  = tid >> 5;
    const int i = i0 + ii;
    const int l = l0 + myl;

    float qr[32];
    const float* qbase = qkv + (h * 32) * SL + i * L_DIM + l;
    #pragma unroll
    for (int c = 0; c < 32; ++c) qr[c] = qbase[c * SL];

    const float* kbase = qkv + (128 + h * 32) * SL + l0;
    const float* vbase = qkv + (256 + h * 32) * SL + l0;

    float m = -__builtin_inff(), lsum = 0.f;
    float o[32];
    #pragma unroll
    for (int d = 0; d < 32; ++d) o[d] = 0.f;

    for (int j0 = 0; j0 < 128; j0 += CJT) {
        __syncthreads();
        // load K,V tiles: 32c x 8j x 32l floats = 2048 float4 each tensor
        for (int idx = tid; idx < 32 * CJT * 8; idx += 256) {
            const int c   = idx >> 6;      // 64 float4 per c (8j x 8 f4)
            const int rem = idx & 63;
            const int jj  = rem >> 3;
            const int l4  = rem & 7;
            *(float4*)&kt[c][jj][l4 * 4] =
                *(const float4*)&kbase[c * SL + (j0 + jj) * L_DIM + l4 * 4];
            *(float4*)&vt[c][jj][l4 * 4] =
                *(const float4*)&vbase[c * SL + (j0 + jj) * L_DIM + l4 * 4];
        }
        __syncthreads();
        #pragma unroll
        for (int jj = 0; jj < CJT; ++jj) {
            float sc = 0.f;
            #pragma unroll
            for (int c = 0; c < 32; ++c) sc += qr[c] * kt[c][jj][myl];
            if (sc > m) {
                const float alpha = __expf(m - sc);
                lsum *= alpha;
                #pragma unroll
                for (int d = 0; d < 32; ++d) o[d] *= alpha;
                m = sc;
            }
            const float p = __expf(sc - m);
            lsum += p;
            #pragma unroll
            for (int d = 0; d < 32; ++d) o[d] += p * vt[d][jj][myl];
        }
    }
    const float inv = 1.f / lsum;
    float* obase = ao + (h * 32) * SL + i * L_DIM + l;
    #pragma unroll
    for (int d = 0; d < 32; ++d) obase[d * SL] = o[d] * inv;
}

// ---------------------------------------------------------------------------
// K3/K6: channel LayerNorm with residual: out = LN(a + r) * gamma + beta
// ---------------------------------------------------------------------------
__global__ __launch_bounds__(256) void ln_kernel(const float* __restrict__ a,
                                                 const float* __restrict__ r,
                                                 const float* __restrict__ gamma,
                                                 const float* __restrict__ beta,
                                                 float* __restrict__ out) {
    const int pos = blockIdx.x * 256 + threadIdx.x;
    float sum = 0.f, sumsq = 0.f;
    #pragma unroll 8
    for (int d = 0; d < 128; ++d) {
        const float v = a[d * SL + pos] + r[d * SL + pos];
        sum += v;
        sumsq += v * v;
    }
    const float mean = sum * (1.f / 128.f);
    const float var  = sumsq * (1.f / 128.f) - mean * mean;
    const float rstd = rsqrtf(var + EPS_LN);
    #pragma unroll 8
    for (int d = 0; d < 128; ++d) {
        const float v = a[d * SL + pos] + r[d * SL + pos];
        out[d * SL + pos] = (v - mean) * rstd * gamma[d] + beta[d];
    }
}

// ---------------------------------------------------------------------------
extern "C" void kernel_launch(void* const* d_in, const int* in_sizes, int n_in,
                              void* d_out, int out_size, void* d_ws, size_t ws_size,
                              hipStream_t stream) {
    const float* x     = (const float*)d_in[0];
    const float* w_row = (const float*)d_in[1];
    const float* b_row = (const float*)d_in[2];
    const float* w_col = (const float*)d_in[3];
    const float* b_col = (const float*)d_in[4];
    const float* g1    = (const float*)d_in[5];
    const float* be1   = (const float*)d_in[6];
    const float* g2    = (const float*)d_in[7];
    const float* be2   = (const float*)d_in[8];
    float* out = (float*)d_out;

    // workspace: qkv (384*SL) | attn_out (128*SL) | out1 (128*SL) = 80 MB
    float* qkv  = (float*)d_ws;
    float* ao   = qkv + 384 * SL;
    float* out1 = ao + 128 * SL;

    qkv_kernel<<<512, 256, 0, stream>>>(x, w_row, b_row, qkv);
    row_attn_kernel<<<512, 256, 0, stream>>>(qkv, ao);
    ln_kernel<<<128, 256, 0, stream>>>(x, ao, g1, be1, out1);
    qkv_kernel<<<512, 256, 0, stream>>>(out1, w_col, b_col, qkv);
    col_attn_kernel<<<512, 256, 0, stream>>>(qkv, ao);
    ln_kernel<<<128, 256, 0, stream>>>(out1, ao, g2, be2, out);
}